// Round 4
// baseline (23953.979 us; speedup 1.0000x reference)
//
#include <hip/hip_runtime.h>
#include <stdint.h>
#include <stddef.h>

// ---------------- problem constants ----------------
#define Bb 64
#define Tt 1024
#define Hh 512
#define Ll 4
#define Gg 2048                 // 4*H
#define NSTEPS (Tt + Ll - 1)    // 1027 wavefront steps
#define NBLK 256                // 64 blocks per layer-group x 4 layers
#define NTHR 256                // 4 waves
#define JBLK 8                  // hidden units per block
#define JROW 520                // padded LDS weight row (bf16): 512 + 8
#define CTR_BYTES 8192
#define HBUF_ELEMS ((size_t)Ll * 2 * Bb * Hh)          // bf16 elements

typedef __bf16 bfrag __attribute__((ext_vector_type(8)));   // 8 bf16 = 4 VGPR (MFMA A/B)
typedef float f32x4 __attribute__((ext_vector_type(4)));    // MFMA C/D

__device__ __forceinline__ float sigm(float x) { return 1.0f / (1.0f + __expf(-x)); }
__device__ __forceinline__ float tanh_(float x) {
    float ax = fabsf(x);
    float e = __expf(-2.0f * ax);
    float r = (1.0f - e) / (1.0f + e);
    return copysignf(r, x);
}

__device__ __forceinline__ void pack8(const float4& x0, const float4& x1, __bf16* dst) {
    union { __bf16 h[8]; uint4 u; } o;
    o.h[0] = (__bf16)x0.x; o.h[1] = (__bf16)x0.y;
    o.h[2] = (__bf16)x0.z; o.h[3] = (__bf16)x0.w;
    o.h[4] = (__bf16)x1.x; o.h[5] = (__bf16)x1.y;
    o.h[6] = (__bf16)x1.z; o.h[7] = (__bf16)x1.w;
    *reinterpret_cast<uint4*>(dst) = o.u;
}

__global__ __launch_bounds__(NTHR, 1)
void lstm_persistent(const float* __restrict__ inp,    // [B,T,H] fp32
                     const float* __restrict__ Wih,    // [L,4H,H] fp32
                     const float* __restrict__ Whh,    // [L,4H,H] fp32
                     const float* __restrict__ bih,    // [L,4H] fp32
                     const float* __restrict__ bhh,    // [L,4H] fp32
                     float* __restrict__ out,          // fp32: [T,B,H] + L*(h,c)[B,H]
                     uint32_t* __restrict__ ctr,       // [NSTEPS] barrier counters (zeroed)
                     __bf16* __restrict__ hbuf)        // [L][2][B][H] bf16 (zeroed)
{
    const int tid  = threadIdx.x;
    const int bx   = blockIdx.x;
    const int l    = bx >> 6;        // layer group 0..3
    const int q    = bx & 63;        // slice within group
    const int j0   = q * JBLK;       // hidden base for this block
    const int w    = tid >> 6;       // wave id == M-tile (batch rows 16w..16w+15)
    const int lane = tid & 63;
    const int ln16 = lane & 15;
    const int quad = lane >> 4;

    // LDS: 66560 + 8448 + 2048 + 128 = 77184 B  (< 160 KiB, 1 block/CU)
    __shared__ __align__(16) __bf16 wlds[2][32][JROW];  // [Wih|Whh][local col][k]
    __shared__ float gatesLds[64][33];   // [batch][32 gate cols], +1 pad col
    __shared__ float cst[64][JBLK];      // cell state fp32, block-private
    __shared__ float biasLds[32];

    // ---- weight preload: fp32 -> bf16 LDS, once per block ----
    // 64 rows (2 mats x 32 local cols); 4 threads per row, 128 k each.
    {
        const int rr   = tid >> 2;       // 0..63
        const int mat  = rr >> 5;        // 0: Wih, 1: Whh
        const int lc   = rr & 31;        // local col: gate*8 + jj
        const int tsub = tid & 3;        // k quarter
        const int gate = lc >> 3, jj = lc & 7;
        const int grow = gate * Hh + j0 + jj;
        const float* W = mat ? Whh : Wih;
        const float* src = W + ((size_t)l * Gg + grow) * Hh + tsub * 128;
        __bf16* drow = &wlds[mat][lc][tsub * 128];
#pragma unroll
        for (int i = 0; i < 128; i += 8) {
            float4 x0 = *reinterpret_cast<const float4*>(src + i);
            float4 x1 = *reinterpret_cast<const float4*>(src + i + 4);
            pack8(x0, x1, drow + i);
        }
    }
    // ---- bias preload (b_ih + b_hh), local col lc = gate*8 + jj ----
    if (tid < 32) {
        int gate = tid >> 3, jj = tid & 7;
        int col = gate * Hh + j0 + jj;
        biasLds[tid] = bih[l * Gg + col] + bhh[l * Gg + col];
    }
    __syncthreads();

    const int brow = w * 16 + ln16;  // batch row this lane loads for A-frags
    const __bf16* wih0 = &wlds[0][ln16][0];       // tile0 cols: i(0-7), f(8-15)
    const __bf16* wih1 = &wlds[0][16 + ln16][0];  // tile1 cols: g(16-23), o(24-31)
    const __bf16* whh0 = &wlds[1][ln16][0];
    const __bf16* whh1 = &wlds[1][16 + ln16][0];

    for (int s = 0; s < NSTEPS; ++s) {
        const int t = s - l;
        const bool active = (t >= 0) && (t < Tt);

        if (active) {
            const int p = (s - 1) & 1;   // parity slot written last step
            f32x4 acc0 = {0.f, 0.f, 0.f, 0.f};
            f32x4 acc1 = {0.f, 0.f, 0.f, 0.f};

            // ---------- phase X: x_t @ Wih^T ----------
            if (l == 0) {
                const float* abase = inp + ((size_t)brow * Tt + t) * Hh;
#pragma unroll
                for (int kk = 0; kk < 16; ++kk) {
                    const int k = kk * 32 + quad * 8;
                    float4 x0 = *reinterpret_cast<const float4*>(abase + k);
                    float4 x1 = *reinterpret_cast<const float4*>(abase + k + 4);
                    bfrag a;
                    a[0] = (__bf16)x0.x; a[1] = (__bf16)x0.y;
                    a[2] = (__bf16)x0.z; a[3] = (__bf16)x0.w;
                    a[4] = (__bf16)x1.x; a[5] = (__bf16)x1.y;
                    a[6] = (__bf16)x1.z; a[7] = (__bf16)x1.w;
                    bfrag b0 = *reinterpret_cast<const bfrag*>(wih0 + k);
                    bfrag b1 = *reinterpret_cast<const bfrag*>(wih1 + k);
                    acc0 = __builtin_amdgcn_mfma_f32_16x16x32_bf16(a, b0, acc0, 0, 0, 0);
                    acc1 = __builtin_amdgcn_mfma_f32_16x16x32_bf16(a, b1, acc1, 0, 0, 0);
                }
            } else {
                const __bf16* abase = hbuf + ((size_t)((l - 1) * 2 + p) * Bb + brow) * Hh;
#pragma unroll
                for (int kk = 0; kk < 16; ++kk) {
                    const int k = kk * 32 + quad * 8;
                    bfrag a  = *reinterpret_cast<const bfrag*>(abase + k);
                    bfrag b0 = *reinterpret_cast<const bfrag*>(wih0 + k);
                    bfrag b1 = *reinterpret_cast<const bfrag*>(wih1 + k);
                    acc0 = __builtin_amdgcn_mfma_f32_16x16x32_bf16(a, b0, acc0, 0, 0, 0);
                    acc1 = __builtin_amdgcn_mfma_f32_16x16x32_bf16(a, b1, acc1, 0, 0, 0);
                }
            }

            // ---------- phase H: h_{t-1} @ Whh^T ----------
            {
                const __bf16* abase = hbuf + ((size_t)(l * 2 + p) * Bb + brow) * Hh;
#pragma unroll
                for (int kk = 0; kk < 16; ++kk) {
                    const int k = kk * 32 + quad * 8;
                    bfrag a  = *reinterpret_cast<const bfrag*>(abase + k);
                    bfrag b0 = *reinterpret_cast<const bfrag*>(whh0 + k);
                    bfrag b1 = *reinterpret_cast<const bfrag*>(whh1 + k);
                    acc0 = __builtin_amdgcn_mfma_f32_16x16x32_bf16(a, b0, acc0, 0, 0, 0);
                    acc1 = __builtin_amdgcn_mfma_f32_16x16x32_bf16(a, b1, acc1, 0, 0, 0);
                }
            }

            // scatter accumulators to LDS: D col=lane&15, row=quad*4+reg (m89-verified)
#pragma unroll
            for (int r = 0; r < 4; ++r) {
                gatesLds[w * 16 + quad * 4 + r][ln16]      = acc0[r];
                gatesLds[w * 16 + quad * 4 + r][16 + ln16] = acc1[r];
            }
        }
        __syncthreads();

        if (active) {
            // elementwise LSTM cell: thread -> (b = tid>>2, jj = (tid&3)*2 .. +1)
            const int b   = tid >> 2;
            const int jjb = (tid & 3) * 2;
            float hv[2], cvv[2];
#pragma unroll
            for (int u2 = 0; u2 < 2; ++u2) {
                const int jj = jjb + u2;
                float iv = gatesLds[b][jj]      + biasLds[jj];
                float fv = gatesLds[b][8 + jj]  + biasLds[8 + jj];
                float gv = gatesLds[b][16 + jj] + biasLds[16 + jj];
                float ov = gatesLds[b][24 + jj] + biasLds[24 + jj];
                float cold = (t == 0) ? 0.0f : cst[b][jj];
                float cnew = sigm(fv) * cold + sigm(iv) * tanh_(gv);
                float h = sigm(ov) * tanh_(cnew);
                cst[b][jj] = cnew;
                cvv[u2] = cnew;
                hv[u2] = h;
            }
            const int jglob = j0 + jjb;

            // publish bf16 h into this step's parity slot (internal exchange)
            union { __bf16 h[2]; uint32_t u; } pk;
            pk.h[0] = (__bf16)hv[0];
            pk.h[1] = (__bf16)hv[1];
            uint32_t* hdst = (uint32_t*)(hbuf + ((size_t)(l * 2 + (s & 1)) * Bb + b) * Hh + jglob);
            *hdst = pk.u;

            // ---- fp32 outputs (reference dtype is float32!) ----
            if (l == Ll - 1) {   // final-layer output x[t,b,:] (time-major)
                float2 xv = make_float2(hv[0], hv[1]);
                *reinterpret_cast<float2*>(out + ((size_t)t * Bb + b) * Hh + jglob) = xv;
            }
            if (t == Tt - 1) {   // final states (hT, cT) per layer, fp32
                const size_t xend = (size_t)Tt * Bb * Hh;
                float2 hv2 = make_float2(hv[0], hv[1]);
                float2 cv2 = make_float2(cvv[0], cvv[1]);
                *reinterpret_cast<float2*>(out + xend + ((size_t)(2 * l) * Bb + b) * Hh + jglob) = hv2;
                *reinterpret_cast<float2*>(out + xend + ((size_t)(2 * l + 1) * Bb + b) * Hh + jglob) = cv2;
            }
        }

        // ---------- grid barrier (step s): release/acquire handshake ----------
        __syncthreads();                       // all block stores issued before arrive
        if (tid == 0) {
            __builtin_amdgcn_fence(__ATOMIC_RELEASE, "agent");   // wbl2: h reaches coherent point
            __hip_atomic_fetch_add(&ctr[s], 1u, __ATOMIC_RELAXED, __HIP_MEMORY_SCOPE_AGENT);
            while (__hip_atomic_load(&ctr[s], __ATOMIC_RELAXED, __HIP_MEMORY_SCOPE_AGENT) < (uint32_t)NBLK) {
                __builtin_amdgcn_s_sleep(1);
            }
            __builtin_amdgcn_fence(__ATOMIC_ACQUIRE, "agent");   // inv: drop stale L1/L2 lines
        }
        __syncthreads();
    }
}

extern "C" void kernel_launch(void* const* d_in, const int* in_sizes, int n_in,
                              void* d_out, int out_size, void* d_ws, size_t ws_size,
                              hipStream_t stream) {
    const float* inp = (const float*)d_in[0];
    const float* Wih = (const float*)d_in[1];
    const float* Whh = (const float*)d_in[2];
    const float* bih = (const float*)d_in[3];
    const float* bhh = (const float*)d_in[4];
    float* out = (float*)d_out;

    uint32_t* ctr  = (uint32_t*)d_ws;
    __bf16*   hbuf = (__bf16*)((char*)d_ws + CTR_BYTES);

    // zero barrier counters + h double-buffers (ws usage: 8 KB + 512 KB only)
    hipMemsetAsync(d_ws, 0, CTR_BYTES + HBUF_ELEMS * sizeof(__bf16), stream);

    lstm_persistent<<<dim3(NBLK), dim3(NTHR), 0, stream>>>(inp, Wih, Whh, bih, bhh,
                                                           out, ctr, hbuf);
}